// Round 1
// baseline (37553.900 us; speedup 1.0000x reference)
//
#include <hip/hip_runtime.h>
#include <hip/hip_bf16.h>

// Problem constants (from reference)
#define B    16
#define TIN  400
#define TT   100
#define EMBD 128
#define EHD  256     // encoder hidden per direction
#define DHD  256     // decoder hidden
#define ADIM 256     // attention dim
#define BND  512     // bottleneck
#define VV   32000
#define NV   31998   // V - END (END = 2)
// token ids: UNK=0, START=1, END=2, PAD=3

__device__ __forceinline__ float sigf(float x) { return 1.f / (1.f + __expf(-x)); }
__device__ __forceinline__ float fast_tanh(float x) {
    float e = __expf(2.f * x);
    return 1.f - 2.f / (e + 1.f);
}

// ---------------------------------------------------------------- zero
__global__ __launch_bounds__(256) void k_zero(float* __restrict__ p, int n) {
    int i = blockIdx.x * 256 + threadIdx.x;
    if (i < n) p[i] = 0.f;
}

// ------------------------------------------------ encoder input GEMM L0
// gx[dir][t][b][c] = emb[safe(ids[b,t])] . Wih0[dir][c,:] + b0[dir][c]
__global__ __launch_bounds__(256) void k_gx0(const int* __restrict__ ids, const float* __restrict__ emb,
                                             const float* __restrict__ Wih, const float* __restrict__ bias,
                                             float* __restrict__ gx) {
    int blk = blockIdx.x, dir = blk / TIN, t = blk % TIN;
    __shared__ float se[16][132];
    int tid = threadIdx.x;
    for (int i = tid; i < 16 * 128; i += 256) {
        int b = i >> 7, k = i & 127;
        int id = ids[b * TIN + t];
        if ((unsigned)id >= VV) id = 0;
        se[b][k] = emb[(size_t)id * EMBD + k];
    }
    __syncthreads();
    const float* W = Wih + (size_t)dir * 1024 * EMBD;
    const float* bb = bias + (size_t)dir * 1024;
    float* out = gx + ((size_t)dir * TIN + t) * (B * 1024);
    for (int c = tid; c < 1024; c += 256) {
        float acc[16];
#pragma unroll
        for (int b = 0; b < 16; b++) acc[b] = 0.f;
        const float4* wr = (const float4*)(W + (size_t)c * EMBD);
        for (int k4 = 0; k4 < 32; k4++) {
            float4 w = wr[k4];
            int k = k4 * 4;
#pragma unroll
            for (int b = 0; b < 16; b++)
                acc[b] += w.x * se[b][k] + w.y * se[b][k + 1] + w.z * se[b][k + 2] + w.w * se[b][k + 3];
        }
        float bv = bb[c];
#pragma unroll
        for (int b = 0; b < 16; b++) out[(size_t)b * 1024 + c] = acc[b] + bv;
    }
}

// ------------------------------------------------ encoder input GEMM L1
// gx[dir][t][b][c] = hseq0[t][b][:512] . Wih1[dir][c,:] + b1[dir][c]
__global__ __launch_bounds__(256) void k_gx1(const float* __restrict__ hseq, const float* __restrict__ Wih,
                                             const float* __restrict__ bias, float* __restrict__ gx) {
    int blk = blockIdx.x, dir = blk / TIN, t = blk % TIN;
    __shared__ float sx[16][516];
    int tid = threadIdx.x;
    for (int i = tid; i < 16 * 512; i += 256) sx[i >> 9][i & 511] = hseq[(size_t)t * B * 512 + i];
    __syncthreads();
    const float* W = Wih + (size_t)dir * 1024 * 512;
    const float* bb = bias + (size_t)dir * 1024;
    float* out = gx + ((size_t)dir * TIN + t) * (B * 1024);
    for (int c = tid; c < 1024; c += 256) {
        float acc[16];
#pragma unroll
        for (int b = 0; b < 16; b++) acc[b] = 0.f;
        const float4* wr = (const float4*)(W + (size_t)c * 512);
        for (int k4 = 0; k4 < 128; k4++) {
            float4 w = wr[k4];
            int k = k4 * 4;
#pragma unroll
            for (int b = 0; b < 16; b++)
                acc[b] += w.x * sx[b][k] + w.y * sx[b][k + 1] + w.z * sx[b][k + 2] + w.w * sx[b][k + 3];
        }
        float bv = bb[c];
#pragma unroll
        for (int b = 0; b < 16; b++) out[(size_t)b * 1024 + c] = acc[b] + bv;
    }
}

// ------------------------------------------------ encoder scan step
// grid 32 = dir(2) x unit-chunk(16); 256 thr = b(16) x u(16)
// hbuf layout [parity][dir][b][256]; cbuf [dir][b][256]
__global__ __launch_bounds__(256) void k_enc_scan(const float* __restrict__ gx, const float* __restrict__ Whh,
                                                  float* __restrict__ hbuf, float* __restrict__ cbuf,
                                                  float* __restrict__ hout, float* __restrict__ hTs,
                                                  float* __restrict__ cTs, int s, int layer) {
    int dir = blockIdx.x >> 4;
    int uc = (blockIdx.x & 15) << 4;
    int tid = threadIdx.x;
    int b = tid & 15, u = tid >> 4;
    int t = dir ? (TIN - 1 - s) : s;
    __shared__ float sh[16][260];
    const float* hp = hbuf + ((size_t)((s & 1) * 2 + dir)) * B * EHD;
    for (int i = tid; i < 16 * 256; i += 256) sh[i >> 8][i & 255] = hp[i];
    __syncthreads();
    int unit = uc + u;
    const float* Wd = Whh + (size_t)dir * 1024 * EHD;
    const float4* wi = (const float4*)(Wd + (size_t)(0 * 256 + unit) * 256);
    const float4* wf = (const float4*)(Wd + (size_t)(1 * 256 + unit) * 256);
    const float4* wg = (const float4*)(Wd + (size_t)(2 * 256 + unit) * 256);
    const float4* wo = (const float4*)(Wd + (size_t)(3 * 256 + unit) * 256);
    const float4* hr = (const float4*)&sh[b][0];
    float ai = 0.f, af = 0.f, ag = 0.f, ao = 0.f;
    for (int k4 = 0; k4 < 64; k4++) {
        float4 hv = hr[k4];
        float4 w;
        w = wi[k4]; ai += w.x * hv.x + w.y * hv.y + w.z * hv.z + w.w * hv.w;
        w = wf[k4]; af += w.x * hv.x + w.y * hv.y + w.z * hv.z + w.w * hv.w;
        w = wg[k4]; ag += w.x * hv.x + w.y * hv.y + w.z * hv.z + w.w * hv.w;
        w = wo[k4]; ao += w.x * hv.x + w.y * hv.y + w.z * hv.z + w.w * hv.w;
    }
    const float* g0 = gx + (((size_t)dir * TIN + t) * B + b) * 1024;
    ai += g0[unit]; af += g0[256 + unit]; ag += g0[512 + unit]; ao += g0[768 + unit];
    float* cp = cbuf + ((size_t)dir * B + b) * EHD + unit;
    float c = *cp;
    c = sigf(af) * c + sigf(ai) * fast_tanh(ag);
    float h = sigf(ao) * fast_tanh(c);
    *cp = c;
    hbuf[((size_t)(((s & 1) ^ 1) * 2 + dir)) * B * EHD + (size_t)b * EHD + unit] = h;
    if (layer == 0)
        hout[((size_t)t * B + b) * 512 + dir * 256 + unit] = h;   // hseq0 [t][b][512]
    else
        hout[((size_t)b * TIN + t) * 512 + dir * 256 + unit] = h; // enc_states [b][t][512]
    if (s == TIN - 1) {
        hTs[((size_t)layer * B + b) * 512 + dir * 256 + unit] = h;
        cTs[((size_t)layer * B + b) * 512 + dir * 256 + unit] = c;
    }
}

// ------------------------------------------------ enc_attn precompute
// encat[b][t][c] = encs[b][t][:] . Wea[c,:] + bea[c];  grid = B*TIN, 256 thr
__global__ __launch_bounds__(256) void k_encattn(const float* __restrict__ encs, const float* __restrict__ Wea,
                                                 const float* __restrict__ bea, float* __restrict__ encat) {
    int blk = blockIdx.x;
    __shared__ float sx[512];
    int tid = threadIdx.x;
    const float* row = encs + (size_t)blk * 512;
    for (int i = tid; i < 512; i += 256) sx[i] = row[i];
    __syncthreads();
    float a = bea[tid];
    const float4* wr = (const float4*)(Wea + (size_t)tid * 512);
    const float4* xr = (const float4*)sx;
    for (int k4 = 0; k4 < 128; k4++) {
        float4 w = wr[k4], x = xr[k4];
        a += w.x * x.x + w.y * x.y + w.z * x.z + w.w * x.w;
    }
    encat[(size_t)blk * 256 + tid] = a;
}

// ------------------------------------------------ decoder init
// dec_h[l] = hT[l] @ W_e2dh.T + b;  dec_c[l] = cT[l] @ W_e2dc.T + b
__global__ __launch_bounds__(256) void k_dec_init(const float* __restrict__ hTs, const float* __restrict__ cTs,
                                                  const float* __restrict__ Wh, const float* __restrict__ bh,
                                                  const float* __restrict__ Wc, const float* __restrict__ bc,
                                                  float* __restrict__ h0buf, float* __restrict__ c0,
                                                  float* __restrict__ h1buf, float* __restrict__ c1) {
    int idx = blockIdx.x * 256 + threadIdx.x; // 8192
    int l = idx >> 12, b = (idx >> 8) & 15, d = idx & 255;
    const float4* h4 = (const float4*)(hTs + ((size_t)l * B + b) * 512);
    const float4* c4 = (const float4*)(cTs + ((size_t)l * B + b) * 512);
    const float4* wh4 = (const float4*)(Wh + (size_t)d * 512);
    const float4* wc4 = (const float4*)(Wc + (size_t)d * 512);
    float ah = bh[d], ac = bc[d];
    for (int k4 = 0; k4 < 128; k4++) {
        float4 w = wh4[k4], x = h4[k4];
        ah += w.x * x.x + w.y * x.y + w.z * x.z + w.w * x.w;
        w = wc4[k4]; x = c4[k4];
        ac += w.x * x.x + w.y * x.y + w.z * x.z + w.w * x.w;
    }
    if (l == 0) { h0buf[(size_t)b * 256 + d] = ah; c0[(size_t)b * 256 + d] = ac; }
    else        { h1buf[(size_t)b * 256 + d] = ah; c1[(size_t)b * 256 + d] = ac; }
}

// ------------------------------------------------ decoder LSTM cell step
// mode 0: x = emb[tok_in[t]] (K=128); mode 1: x = xbuf (h0 new, K=256)
// hpair layout [parity][b][256]
__global__ __launch_bounds__(256) void k_dec_cell(const int* __restrict__ tgt, const float* __restrict__ emb,
                                                  const float* __restrict__ xbuf, const float* __restrict__ Wih,
                                                  const float* __restrict__ Whh, const float* __restrict__ bias,
                                                  float* __restrict__ hpair, float* __restrict__ cst,
                                                  int t, int mode) {
    int tid = threadIdx.x;
    int b = tid & 15, u = tid >> 4;
    int unit = blockIdx.x * 16 + u;
    int r = t & 1, w = r ^ 1;
    __shared__ float sx[16][260];
    __shared__ float sh[16][260];
    if (mode == 0) {
        for (int i = tid; i < 16 * 128; i += 256) {
            int bb = i >> 7, k = i & 127;
            int tok = (t == 0) ? 1 : tgt[bb * TT + t - 1];
            if ((unsigned)tok >= VV) tok = 0;
            sx[bb][k] = emb[(size_t)tok * EMBD + k];
        }
    } else {
        for (int i = tid; i < 16 * 256; i += 256) sx[i >> 8][i & 255] = xbuf[i];
    }
    const float* hp = hpair + (size_t)r * B * 256;
    for (int i = tid; i < 16 * 256; i += 256) sh[i >> 8][i & 255] = hp[i];
    __syncthreads();
    float ai = bias[unit], af = bias[256 + unit], ag = bias[512 + unit], ao = bias[768 + unit];
    const int KX = mode ? 256 : 128;
    {
        const float4* xi = (const float4*)(Wih + (size_t)(0 * 256 + unit) * KX);
        const float4* xf = (const float4*)(Wih + (size_t)(1 * 256 + unit) * KX);
        const float4* xg = (const float4*)(Wih + (size_t)(2 * 256 + unit) * KX);
        const float4* xo = (const float4*)(Wih + (size_t)(3 * 256 + unit) * KX);
        const float4* xv = (const float4*)&sx[b][0];
        int n4 = KX >> 2;
        for (int k4 = 0; k4 < n4; k4++) {
            float4 x = xv[k4];
            float4 w;
            w = xi[k4]; ai += w.x * x.x + w.y * x.y + w.z * x.z + w.w * x.w;
            w = xf[k4]; af += w.x * x.x + w.y * x.y + w.z * x.z + w.w * x.w;
            w = xg[k4]; ag += w.x * x.x + w.y * x.y + w.z * x.z + w.w * x.w;
            w = xo[k4]; ao += w.x * x.x + w.y * x.y + w.z * x.z + w.w * x.w;
        }
    }
    {
        const float4* wi = (const float4*)(Whh + (size_t)(0 * 256 + unit) * 256);
        const float4* wf = (const float4*)(Whh + (size_t)(1 * 256 + unit) * 256);
        const float4* wg = (const float4*)(Whh + (size_t)(2 * 256 + unit) * 256);
        const float4* wo = (const float4*)(Whh + (size_t)(3 * 256 + unit) * 256);
        const float4* hv4 = (const float4*)&sh[b][0];
        for (int k4 = 0; k4 < 64; k4++) {
            float4 h = hv4[k4];
            float4 w;
            w = wi[k4]; ai += w.x * h.x + w.y * h.y + w.z * h.z + w.w * h.w;
            w = wf[k4]; af += w.x * h.x + w.y * h.y + w.z * h.z + w.w * h.w;
            w = wg[k4]; ag += w.x * h.x + w.y * h.y + w.z * h.z + w.w * h.w;
            w = wo[k4]; ao += w.x * h.x + w.y * h.y + w.z * h.z + w.w * h.w;
        }
    }
    float* cp = cst + (size_t)b * 256 + unit;
    float c = *cp;
    c = sigf(af) * c + sigf(ai) * fast_tanh(ag);
    float h = sigf(ao) * fast_tanh(c);
    *cp = c;
    hpair[(size_t)w * B * 256 + (size_t)b * 256 + unit] = h;
}

// ------------------------------------------------ attention step (one block per b)
__global__ __launch_bounds__(256) void k_attn(const int* __restrict__ ids, const int* __restrict__ tgt,
                                              const int* __restrict__ tlen, const float* __restrict__ encat,
                                              const float* __restrict__ encs, const float* __restrict__ Wda,
                                              const float* __restrict__ wcov, const float* __restrict__ vat,
                                              const float* __restrict__ h1buf, float* __restrict__ coverage,
                                              float* __restrict__ ctx, float* __restrict__ pcopy,
                                              float* __restrict__ cov, int t) {
    int b = blockIdx.x;
    int tid = threadIdx.x;
    int w = (t & 1) ^ 1;
    __shared__ float sh1[256];
    __shared__ float sda[256];
    __shared__ float ssc[TIN];
    __shared__ float red[256];
    sh1[tid] = h1buf[(size_t)w * B * 256 + (size_t)b * 256 + tid];
    __syncthreads();
    { // dec_attn = h1 @ W_dec_attn.T
        float a = 0.f;
        const float4* wr = (const float4*)(Wda + (size_t)tid * 256);
        const float4* h4 = (const float4*)sh1;
        for (int k4 = 0; k4 < 64; k4++) {
            float4 ww = wr[k4], x = h4[k4];
            a += ww.x * x.x + ww.y * x.y + ww.z * x.z + ww.w * x.w;
        }
        sda[tid] = a;
    }
    __syncthreads();
    int lane = tid & 63, wv = tid >> 6;
    for (int tt = wv; tt < TIN; tt += 4) {
        float cvv = coverage[b * TIN + tt];
        const float* ea = encat + ((size_t)b * TIN + tt) * 256;
        float s4 = 0.f;
#pragma unroll
        for (int j = 0; j < 4; j++) {
            int c = lane + 64 * j;
            float x = ea[c] + sda[c] + cvv * wcov[c];
            s4 += vat[c] * fast_tanh(x);
        }
#pragma unroll
        for (int o = 32; o > 0; o >>= 1) s4 += __shfl_xor(s4, o, 64);
        if (lane == 0) ssc[tt] = (ids[b * TIN + tt] == 3) ? -1e30f : s4;
    }
    __syncthreads();
    // softmax over 400
    float m = -1e30f;
    for (int i = tid; i < TIN; i += 256) m = fmaxf(m, ssc[i]);
    red[tid] = m; __syncthreads();
    for (int o = 128; o > 0; o >>= 1) { if (tid < o) red[tid] = fmaxf(red[tid], red[tid + o]); __syncthreads(); }
    m = red[0]; __syncthreads();
    float ps = 0.f;
    for (int i = tid; i < TIN; i += 256) { float e = __expf(ssc[i] - m); ssc[i] = e; ps += e; }
    red[tid] = ps; __syncthreads();
    for (int o = 128; o > 0; o >>= 1) { if (tid < o) red[tid] += red[tid + o]; __syncthreads(); }
    float inv = 1.f / red[0];
    __syncthreads();
    int tgb = tgt[b * TT + t];
    float pc = 0.f, ca = 0.f;
    for (int i = tid; i < TIN; i += 256) {
        float at = ssc[i] * inv; ssc[i] = at;
        float cv = coverage[b * TIN + i];
        ca += fminf(at, cv);
        coverage[b * TIN + i] = cv + at;
        if (ids[b * TIN + i] == tgb) pc += at;
    }
    red[tid] = pc; __syncthreads();
    for (int o = 128; o > 0; o >>= 1) { if (tid < o) red[tid] += red[tid + o]; __syncthreads(); }
    if (tid == 0) pcopy[b] = red[0];
    __syncthreads();
    red[tid] = ca; __syncthreads();
    for (int o = 128; o > 0; o >>= 1) { if (tid < o) red[tid] += red[tid + o]; __syncthreads(); }
    if (tid == 0 && t < tlen[b]) cov[b] += red[0];
    __syncthreads();
    // ctx = attn @ enc_states[b]
    for (int d = tid; d < 512; d += 256) {
        float acc = 0.f;
        const float* es = encs + (size_t)b * TIN * 512 + d;
#pragma unroll 4
        for (int i = 0; i < TIN; i++) acc += ssc[i] * es[(size_t)i * 512];
        ctx[(size_t)b * 512 + d] = acc;
    }
}

// ------------------------------------------------ fc1 = relu([h1,ctx] @ W_v1.T + b)
__global__ __launch_bounds__(256) void k_fc1(const float* __restrict__ h1buf, const float* __restrict__ ctxp,
                                             const float* __restrict__ W, const float* __restrict__ bias,
                                             float* __restrict__ fc1, int t) {
    __shared__ float sx[16][772];
    int tid = threadIdx.x;
    int w = (t & 1) ^ 1;
    for (int i = tid; i < 16 * 256; i += 256) sx[i >> 8][i & 255] = h1buf[(size_t)w * B * 256 + i];
    for (int i = tid; i < 16 * 512; i += 256) sx[i >> 9][256 + (i & 511)] = ctxp[i];
    __syncthreads();
    int b = tid & 15, cl = tid >> 4;
    int c = blockIdx.x * 16 + cl;
    float a = bias[c];
    const float4* wr = (const float4*)(W + (size_t)c * 768);
    const float4* xr = (const float4*)&sx[b][0];
    for (int k4 = 0; k4 < 192; k4++) {
        float4 ww = wr[k4], x = xr[k4];
        a += ww.x * x.x + ww.y * x.y + ww.z * x.z + ww.w * x.w;
    }
    fc1[(size_t)b * 512 + c] = fmaxf(a, 0.f);
}

// ------------------------------------------------ vocab logits + partial exp-sums
// grid 250; 256 thr = vl(128) x kh(2); v = blk*128+vl; each thread: 16 batch accums
__global__ __launch_bounds__(256) void k_vocab(const float* __restrict__ fc1, const float* __restrict__ W2,
                                               const float* __restrict__ b2, const int* __restrict__ tgt,
                                               float* __restrict__ vpart, float* __restrict__ ltgt, int t) {
    __shared__ float sf[16][512];
    __shared__ float half_[128][17];
    int tid = threadIdx.x;
    for (int i = tid; i < 16 * 512; i += 256) sf[i >> 9][i & 511] = fc1[i];
    __syncthreads();
    int vl = tid & 127, kh = tid >> 7;
    int v = blockIdx.x * 128 + vl;
    float acc[16];
#pragma unroll
    for (int b = 0; b < 16; b++) acc[b] = 0.f;
    if (v < NV) {
        const float4* wr = (const float4*)(W2 + (size_t)v * 512 + (size_t)kh * 256);
        for (int k4 = 0; k4 < 64; k4++) {
            float4 w = wr[k4];
            int k = kh * 256 + k4 * 4;
#pragma unroll
            for (int b = 0; b < 16; b++)
                acc[b] += w.x * sf[b][k] + w.y * sf[b][k + 1] + w.z * sf[b][k + 2] + w.w * sf[b][k + 3];
        }
    }
    if (kh == 1) {
#pragma unroll
        for (int b = 0; b < 16; b++) half_[vl][b] = acc[b];
    }
    __syncthreads();
    if (kh == 0) {
        if (v < NV) {
            float bias = b2[v];
#pragma unroll
            for (int b = 0; b < 16; b++) {
                float lg = acc[b] + half_[vl][b] + bias;
                if (tgt[b * TT + t] - 2 == v) ltgt[b] = lg;
                acc[b] = __expf(lg);
            }
        }
        // else acc stays 0 (contributes nothing)
    }
    __syncthreads();
    if (kh == 0) {
#pragma unroll
        for (int b = 0; b < 16; b++) half_[vl][b] = acc[b];
    }
    __syncthreads();
    { // reduce 128 -> 16 per b
        int b = tid >> 4, sl = tid & 15;
        float s = 0.f;
#pragma unroll
        for (int j = 0; j < 8; j++) s += half_[sl + 16 * j][b];
        sf[b][sl] = s;
    }
    __syncthreads();
    if (tid < 16) {
        float den = 0.f;
#pragma unroll
        for (int j = 0; j < 16; j++) den += sf[tid][j];
        vpart[(size_t)tid * 250 + blockIdx.x] = den;
    }
}

// ------------------------------------------------ finalize step: p_gen, p, nll
__global__ __launch_bounds__(256) void k_final(const float* __restrict__ vpart, const float* __restrict__ ltgt,
                                               const float* __restrict__ pcopy, const float* __restrict__ ctxp,
                                               const float* __restrict__ h1buf, const int* __restrict__ tgt,
                                               const int* __restrict__ tlen, const float* __restrict__ emb,
                                               const float* __restrict__ wctx, const float* __restrict__ bctx,
                                               const float* __restrict__ wdec, const float* __restrict__ wemb,
                                               float* __restrict__ nll, const float* __restrict__ cov,
                                               float* __restrict__ out, int t) {
    int tid = threadIdx.x;
    int lane = tid & 63, wv = tid >> 6;
    int w = (t & 1) ^ 1;
    __shared__ float sgen[16];
    __shared__ float sden[16][17];
    for (int bi = 0; bi < 4; bi++) {
        int b = wv * 4 + bi;
        float a = 0.f;
        const float* cx = ctxp + (size_t)b * 512;
        for (int k = lane; k < 512; k += 64) a += cx[k] * wctx[k];
        const float* h1 = h1buf + (size_t)w * B * 256 + (size_t)b * 256;
        for (int k = lane; k < 256; k += 64) a += h1[k] * wdec[k];
        int tok = (t == 0) ? 1 : tgt[b * TT + t - 1];
        if ((unsigned)tok >= VV) tok = 0;
        const float* e = emb + (size_t)tok * EMBD;
        for (int k = lane; k < 128; k += 64) a += e[k] * wemb[k];
#pragma unroll
        for (int o = 32; o > 0; o >>= 1) a += __shfl_xor(a, o, 64);
        if (lane == 0) sgen[b] = a;
    }
    {
        int b = tid >> 4, sl = tid & 15;
        float s = 0.f;
        for (int j = sl; j < 250; j += 16) s += vpart[(size_t)b * 250 + j];
        sden[b][sl] = s;
    }
    __syncthreads();
    if (tid < 16) {
        int b = tid;
        float den = 0.f;
#pragma unroll
        for (int j = 0; j < 16; j++) den += sden[b][j];
        float pg = 1.f / (1.f + __expf(-(sgen[b] + bctx[0])));
        int tg = tgt[b * TT + t];
        float pv = (tg >= 2) ? (__expf(ltgt[b]) / den) : 0.f;
        float p = pg * pv + (1.f - pg) * pcopy[b];
        if (t < tlen[b]) nll[b] += -logf(p + 1e-9f);
    }
    if (t == TT - 1) {
        __syncthreads();
        if (tid == 0) {
            float sn = 0.f, sc = 0.f;
            for (int b = 0; b < 16; b++) { sn += nll[b]; sc += cov[b]; }
            out[0] = sn; out[1] = sc; out[2] = sn + sc;
        }
    }
}

// ================================================================ host
extern "C" void kernel_launch(void* const* d_in, const int* in_sizes, int n_in,
                              void* d_out, int out_size, void* d_ws, size_t ws_size,
                              hipStream_t stream) {
    (void)in_sizes; (void)n_in; (void)out_size; (void)ws_size;
    const int*   ids   = (const int*)d_in[0];
    const int*   tgt   = (const int*)d_in[1];
    const int*   tlen  = (const int*)d_in[3];
    const float* emb   = (const float*)d_in[4];
    const float* eWih0 = (const float*)d_in[5];
    const float* eWhh0 = (const float*)d_in[6];
    const float* eb0   = (const float*)d_in[7];
    const float* eWih1 = (const float*)d_in[8];
    const float* eWhh1 = (const float*)d_in[9];
    const float* eb1   = (const float*)d_in[10];
    const float* We2dh = (const float*)d_in[11];
    const float* be2dh = (const float*)d_in[12];
    const float* We2dc = (const float*)d_in[13];
    const float* be2dc = (const float*)d_in[14];
    const float* dWih0 = (const float*)d_in[15];
    const float* dWhh0 = (const float*)d_in[16];
    const float* db0   = (const float*)d_in[17];
    const float* dWih1 = (const float*)d_in[18];
    const float* dWhh1 = (const float*)d_in[19];
    const float* db1   = (const float*)d_in[20];
    const float* Wea   = (const float*)d_in[21];
    const float* bea   = (const float*)d_in[22];
    const float* Wda   = (const float*)d_in[23];
    const float* wcov  = (const float*)d_in[24];
    const float* vat   = (const float*)d_in[25];
    const float* Wv1   = (const float*)d_in[26];
    const float* bv1   = (const float*)d_in[27];
    const float* Wv2   = (const float*)d_in[28];
    const float* bv2   = (const float*)d_in[29];
    const float* wctx  = (const float*)d_in[30];
    const float* bctx  = (const float*)d_in[31];
    const float* wdec  = (const float*)d_in[32];
    const float* wemb  = (const float*)d_in[33];
    float* out = (float*)d_out;

    // workspace carve-up (floats); total ~21.5M floats (~86 MB)
    float* ws = (float*)d_ws;
    float* GX    = ws; ws += (size_t)2 * TIN * B * 1024; // 13,107,200
    float* HSEQ  = ws; ws += (size_t)TIN * B * 512;      //  3,276,800
    float* ENCS  = ws; ws += (size_t)B * TIN * 512;      //  3,276,800
    float* ENCAT = ws; ws += (size_t)B * TIN * 256;      //  1,638,400
    float* HBUF  = ws; ws += 2 * 2 * B * 256;            // 16,384 (zeroed w/ CBUF)
    float* CBUF  = ws; ws += 2 * B * 256;                //  8,192
    float* HTS   = ws; ws += 2 * B * 512;
    float* CTS   = ws; ws += 2 * B * 512;
    float* H0    = ws; ws += 2 * B * 256;
    float* C0    = ws; ws += B * 256;
    float* H1    = ws; ws += 2 * B * 256;
    float* C1    = ws; ws += B * 256;
    float* COVG  = ws; ws += B * TIN;                    // zeroed w/ NLL, COVL
    float* NLL   = ws; ws += B;
    float* COVL  = ws; ws += B;
    float* CTX   = ws; ws += B * 512;
    float* FC1   = ws; ws += B * 512;
    float* PCOPY = ws; ws += B;
    float* VPART = ws; ws += (size_t)B * 250;
    float* LTGT  = ws; ws += B;

    // ---- encoder layer 0
    k_zero<<<96, 256, 0, stream>>>(HBUF, 24576);  // HBUF + CBUF (contiguous)
    k_zero<<<26, 256, 0, stream>>>(COVG, 6432);   // COVG + NLL + COVL (contiguous)
    k_gx0<<<2 * TIN, 256, 0, stream>>>(ids, emb, eWih0, eb0, GX);
    for (int s = 0; s < TIN; s++)
        k_enc_scan<<<32, 256, 0, stream>>>(GX, eWhh0, HBUF, CBUF, HSEQ, HTS, CTS, s, 0);
    // ---- encoder layer 1
    k_gx1<<<2 * TIN, 256, 0, stream>>>(HSEQ, eWih1, eb1, GX);
    k_zero<<<96, 256, 0, stream>>>(HBUF, 24576);
    for (int s = 0; s < TIN; s++)
        k_enc_scan<<<32, 256, 0, stream>>>(GX, eWhh1, HBUF, CBUF, ENCS, HTS, CTS, s, 1);
    // ---- attention precompute + decoder init
    k_encattn<<<B * TIN, 256, 0, stream>>>(ENCS, Wea, bea, ENCAT);
    k_dec_init<<<32, 256, 0, stream>>>(HTS, CTS, We2dh, be2dh, We2dc, be2dc, H0, C0, H1, C1);
    // ---- decoder loop
    for (int t = 0; t < TT; t++) {
        int w = (t & 1) ^ 1;
        k_dec_cell<<<16, 256, 0, stream>>>(tgt, emb, nullptr, dWih0, dWhh0, db0, H0, C0, t, 0);
        k_dec_cell<<<16, 256, 0, stream>>>(tgt, emb, H0 + (size_t)w * B * 256, dWih1, dWhh1, db1, H1, C1, t, 1);
        k_attn<<<B, 256, 0, stream>>>(ids, tgt, tlen, ENCAT, ENCS, Wda, wcov, vat, H1, COVG, CTX, PCOPY, COVL, t);
        k_fc1<<<32, 256, 0, stream>>>(H1, CTX, Wv1, bv1, FC1, t);
        k_vocab<<<250, 256, 0, stream>>>(FC1, Wv2, bv2, tgt, VPART, LTGT, t);
        k_final<<<1, 256, 0, stream>>>(VPART, LTGT, PCOPY, CTX, H1, tgt, tlen, emb,
                                       wctx, bctx, wdec, wemb, NLL, COVL, out, t);
    }
}